// Round 7
// baseline (1193.914 us; speedup 1.0000x reference)
//
#include <hip/hip_runtime.h>
#include <stdint.h>

typedef __attribute__((ext_vector_type(8))) short short8;
typedef __attribute__((ext_vector_type(8))) unsigned short ushort8_t;
typedef __attribute__((ext_vector_type(4))) float floatx4;

#define T1 127
#define ENC 256
#define HD 256

// workspace offsets (bytes)
#define WHI_OFF   0u            // 1024*256 ushort = 524288
#define WLO_OFF   524288u
#define D0_OFF    1048576u      // 512*128 u64 = 524288  (epoch-tagged d words)
#define D1_OFF    1572864u
#define WEFF_OFF  2097152u      // 256 floats
#define YT_OFF    2099200u      // 512*128 fp32 = 262144
#define CTX_OFF   2361344u      // 512*256 fp32 = 524288
#define DT_OFF    2885632u      // 512*256 fp32 = 524288

__device__ __forceinline__ void split_bf16(float x, unsigned& hi, unsigned& lo) {
    unsigned u = __float_as_uint(x);
    hi = u >> 16;
    float hf = __uint_as_float(hi << 16);
    float r = x - hf;
    unsigned ur = __float_as_uint(r);
    lo = (ur + 0x7fffu + ((ur >> 16) & 1u)) >> 16;
}

__device__ __forceinline__ float sigm_f(float x) { return 1.f / (1.f + __expf(-x)); }
__device__ __forceinline__ float tanh_f(float x) {
    x = fminf(9.f, fmaxf(-9.f, x));
    float e = __expf(2.f * x);
    return (e - 1.f) / (e + 1.f);
}

// 64-byte line load, L1-bypass but L2-served (sc0 only) — the intra-XCD fast path.
// Single asm block (loads + waitcnt) so all operands are plain "=v" outputs;
// tied indirect register tuples are not supported by the gfx950 backend (R6 fail).
__device__ __forceinline__ void load64_sc0(const unsigned long long* p,
                                           uint4& a, uint4& b, uint4& c, uint4& d) {
    asm volatile("global_load_dwordx4 %0, %4, off sc0\n\t"
                 "global_load_dwordx4 %1, %4, off offset:16 sc0\n\t"
                 "global_load_dwordx4 %2, %4, off offset:32 sc0\n\t"
                 "global_load_dwordx4 %3, %4, off offset:48 sc0\n\t"
                 "s_waitcnt vmcnt(0)"
                 : "=v"(a), "=v"(b), "=v"(c), "=v"(d)
                 : "v"((unsigned long long)p)
                 : "memory");
}

// ---------------- k_prep: weight collapse + W_hh hi/lo split + init ----------------
__global__ __launch_bounds__(256) void k_prep(const float* __restrict__ W1,
                                              const float* __restrict__ W2,
                                              const float* __restrict__ W_hh,
                                              char* __restrict__ ws) {
    const int tid = threadIdx.x, bid = blockIdx.x;
    ushort* Whi = (ushort*)(ws + WHI_OFF);
    ushort* Wlo = (ushort*)(ws + WLO_OFF);
    {
        const int i4 = bid * 256 + tid;   // 0..65535
        float4 v = ((const float4*)W_hh)[i4];
        float vv[4] = {v.x, v.y, v.z, v.w};
        unsigned h[4], l[4];
        #pragma unroll
        for (int j = 0; j < 4; ++j) split_bf16(vv[j], h[j], l[j]);
        *(ushort4*)(Whi + i4 * 4) = make_ushort4((ushort)h[0], (ushort)h[1], (ushort)h[2], (ushort)h[3]);
        *(ushort4*)(Wlo + i4 * 4) = make_ushort4((ushort)l[0], (ushort)l[1], (ushort)l[2], (ushort)l[3]);
    }
    {
        const int idx = bid * 256 + tid;
        if (idx < 32768) ((uint4*)(ws + D0_OFF))[idx] = make_uint4(0, 0, 0, 0);
    }
    if (bid == 0) {
        float acc = 0.f;
        for (int j = 0; j < 128; ++j)
            acc = fmaf(W2[j], W1[j * 768 + 512 + tid], acc);
        ((float*)(ws + WEFF_OFF))[tid] = acc;
    }
}

// ---------------- k_attn: scores -> softmax -> context -> y_tilde ----------------
__global__ __launch_bounds__(256) void k_attn(const float* __restrict__ X,
                                              const float* __restrict__ y_prev,
                                              const float* __restrict__ W_fc,
                                              const float* __restrict__ b_fc,
                                              char* __restrict__ ws) {
    __shared__ float s_lds[128];
    __shared__ float beta[128];
    __shared__ float red[256];
    const int b = blockIdx.x, tid = threadIdx.x;
    const int w = tid >> 6, lane = tid & 63;
    const float* Xb = X + (size_t)b * T1 * ENC;
    const float* weff = (const float*)(ws + WEFF_OFF);
    const float4 w4 = ((const float4*)weff)[lane];
    for (int i = 0; i < 32; ++i) {
        int t = w * 32 + i;
        if (t >= T1) break;
        float4 x4 = ((const float4*)(Xb + t * ENC))[lane];
        float a = x4.x * w4.x + x4.y * w4.y + x4.z * w4.z + x4.w * w4.w;
        for (int m = 32; m >= 1; m >>= 1) a += __shfl_xor(a, m, 64);
        if (lane == 0) s_lds[t] = a;
    }
    __syncthreads();
    if (w == 0) {
        float v0 = s_lds[lane];
        float v1 = (lane + 64 < T1) ? s_lds[lane + 64] : -1e30f;
        float mx = fmaxf(v0, v1);
        for (int m = 32; m >= 1; m >>= 1) mx = fmaxf(mx, __shfl_xor(mx, m, 64));
        float e0 = __expf(v0 - mx);
        float e1 = (lane + 64 < T1) ? __expf(v1 - mx) : 0.f;
        float s = e0 + e1;
        for (int m = 32; m >= 1; m >>= 1) s += __shfl_xor(s, m, 64);
        float inv = 1.f / s;
        beta[lane] = e0 * inv;
        if (lane + 64 < T1) beta[lane + 64] = e1 * inv;
    }
    __syncthreads();
    float acc = 0.f;
    for (int t = 0; t < T1; ++t) acc = fmaf(beta[t], Xb[t * ENC + tid], acc);
    ((float*)(ws + CTX_OFF))[b * ENC + tid] = acc;
    red[tid] = acc * W_fc[tid];
    __syncthreads();
    for (int s = 128; s >= 1; s >>= 1) { if (tid < s) red[tid] += red[tid + s]; __syncthreads(); }
    const float u = red[0] + b_fc[0];
    const float wy = W_fc[256];
    if (tid < T1)
        ((float*)(ws + YT_OFF))[b * 128 + tid] = u + wy * y_prev[b * T1 + tid];
}

// ---------------- k_lstm: persistent LSTM, same-XCD L2 fast path + IC fallback ----------------
// Groups of 8 blocks chosen with equal bid%8 (likely same XCD under round-robin
// dispatch): gi = (bid&7)*4 + (bid>>6), hj = (bid>>3)&7.
// Producers dual-publish each epoch-tagged u64: plain store (XCD-shared L2) +
// agent-scope store (IC). Consumers poll with sc0-only loads (L2-served); on
// 24-round timeout a sticky per-thread flag falls back to the R5 agent path.
// Misplacement only costs speed, never correctness.
__global__ __launch_bounds__(256, 1) void k_lstm(const float* __restrict__ W_ih,
                                                 const float* __restrict__ b_ih,
                                                 const float* __restrict__ b_hh,
                                                 char* __restrict__ ws) {
    __shared__ __align__(16) ushort ldh[16 * 264];
    __shared__ __align__(16) ushort ldl[16 * 264];
    __shared__ float gbuf[16 * 132];

    const int tid = threadIdx.x, bid = blockIdx.x;
    const int gi = (bid & 7) * 4 + (bid >> 6);
    const int hj = (bid >> 3) & 7;
    const int w = tid >> 6, lane = tid & 63;
    const int n16 = lane & 15, q = lane >> 4;

    const ushort* Whi = (const ushort*)(ws + WHI_OFF);
    const ushort* Wlo = (const ushort*)(ws + WLO_OFF);
    unsigned long long* Dbuf0 = (unsigned long long*)(ws + D0_OFF);
    unsigned long long* Dbuf1 = (unsigned long long*)(ws + D1_OFF);
    const float* yt = (const float*)(ws + YT_OFF);
    float* dT = (float*)(ws + DT_OFF);

    // resident W fragments: wave w owns N-tiles {2w, 2w+1}; row r = hloc*4 + g
    short8 bfh[2][8], bfl[2][8];
    #pragma unroll
    for (int j = 0; j < 2; ++j) {
        const int r = (2 * w + j) * 16 + n16;          // 0..127
        const int hloc = r >> 2, g = r & 3;
        const int R = g * 256 + hj * 32 + hloc;        // global gate row
        #pragma unroll
        for (int kt = 0; kt < 8; ++kt) {
            bfh[j][kt] = *(const short8*)(Whi + R * 256 + kt * 32 + q * 8);
            bfl[j][kt] = *(const short8*)(Wlo + R * 256 + kt * 32 + q * 8);
        }
    }

    // cell assignment: 16 batches x 32 h = 512 cells, 2 per thread
    const int b_loc = tid & 15, hpair = tid >> 4;      // hpair 0..15
    const int hloc0 = hpair * 2;
    const int bg = gi * 16 + b_loc;
    float wihr[2][4], bihr[2][4];
    #pragma unroll
    for (int jj = 0; jj < 2; ++jj)
        #pragma unroll
        for (int g = 0; g < 4; ++g) {
            const int row = g * HD + hj * 32 + hloc0 + jj;
            wihr[jj][g] = W_ih[row];
            bihr[jj][g] = b_ih[row] + b_hh[row];
        }
    float cc0 = 0.f, cc1 = 0.f;

    // poll/stage assignment: thread covers batch pb = tid>>4, hp8 = tid&15
    const int pb = tid >> 4, hp8 = tid & 15;
    const bool own = ((hp8 >> 1) == hj);
    const size_t pbase = (size_t)(gi * 16 + pb) * 128 + hp8 * 8;
    bool fast = true;    // sticky: same-XCD L2 path assumed until proven otherwise

    {
        ushort8_t z = {0, 0, 0, 0, 0, 0, 0, 0};
        *(ushort8_t*)(ldh + pb * 264 + hp8 * 16)     = z;
        *(ushort8_t*)(ldh + pb * 264 + hp8 * 16 + 8) = z;
        *(ushort8_t*)(ldl + pb * 264 + hp8 * 16)     = z;
        *(ushort8_t*)(ldl + pb * 264 + hp8 * 16 + 8) = z;
    }

    for (int t = 1; t <= T1; ++t) {
        const float ytv = yt[bg * 128 + (t - 1)];   // prefetch, independent of d
        if (!own) {
            unsigned long long* Dsrc = ((t - 1) & 1) ? Dbuf1 : Dbuf0;
            const unsigned e = (unsigned)(t - 1) & 3u;
            unsigned lo[8], hi[8];
            bool got = false;
            if (fast) {
                // ---- fast path: sc0-only line poll (L2-served) ----
                for (int rr = 0; rr < 24; ++rr) {
                    uint4 A, B, C, D;
                    load64_sc0(&Dsrc[pbase], A, B, C, D);
                    lo[0] = A.x; hi[0] = A.y; lo[1] = A.z; hi[1] = A.w;
                    lo[2] = B.x; hi[2] = B.y; lo[3] = B.z; hi[3] = B.w;
                    lo[4] = C.x; hi[4] = C.y; lo[5] = C.z; hi[5] = C.w;
                    lo[6] = D.x; hi[6] = D.y; lo[7] = D.z; hi[7] = D.w;
                    bool ok = true;
                    #pragma unroll
                    for (int i = 0; i < 8; ++i) {
                        unsigned ep = (lo[i] & 1u) | ((hi[i] & 1u) << 1);
                        ok &= (ep == e);
                    }
                    if (ok) { got = true; break; }
                    __builtin_amdgcn_s_sleep(1);
                }
                if (!got) fast = false;   // cross-XCD: sticky fallback
            }
            if (!got) {
                // ---- fallback: agent-scope (IC) stale-only poll, proven in R5 ----
                unsigned long long wv[8];
                #pragma unroll
                for (int i = 0; i < 8; ++i)
                    wv[i] = __hip_atomic_load(&Dsrc[pbase + i], __ATOMIC_RELAXED,
                                              __HIP_MEMORY_SCOPE_AGENT);
                unsigned stale = 0xFFu;
                for (;;) {
                    unsigned ns = 0;
                    #pragma unroll
                    for (int i = 0; i < 8; ++i)
                        if (stale & (1u << i)) {
                            unsigned ep = (unsigned)(wv[i] & 1ull) |
                                          (((unsigned)(wv[i] >> 32) & 1u) << 1);
                            if (ep != e) ns |= 1u << i;
                        }
                    if (!ns) break;
                    __builtin_amdgcn_s_sleep(1);
                    #pragma unroll
                    for (int i = 0; i < 8; ++i)
                        if (ns & (1u << i))
                            wv[i] = __hip_atomic_load(&Dsrc[pbase + i], __ATOMIC_RELAXED,
                                                      __HIP_MEMORY_SCOPE_AGENT);
                    stale = ns;
                }
                #pragma unroll
                for (int i = 0; i < 8; ++i) {
                    lo[i] = (unsigned)wv[i];
                    hi[i] = (unsigned)(wv[i] >> 32);
                }
            }
            // decode: 16 hi + 16 lo ushorts -> two b128 stores per plane
            ushort hv[16], lv[16];
            #pragma unroll
            for (int i = 0; i < 8; ++i) {
                hv[2 * i]     = (ushort)(lo[i] >> 16);
                hv[2 * i + 1] = (ushort)(hi[i] >> 16);
                lv[2 * i]     = (ushort)(lo[i] & 0xFFFEu);
                lv[2 * i + 1] = (ushort)(hi[i] & 0xFFFEu);
            }
            ushort8_t H0, L0, H1, L1;
            #pragma unroll
            for (int i = 0; i < 8; ++i) { H0[i] = hv[i]; L0[i] = lv[i]; H1[i] = hv[8 + i]; L1[i] = lv[8 + i]; }
            *(ushort8_t*)(ldh + pb * 264 + hp8 * 16)     = H0;
            *(ushort8_t*)(ldh + pb * 264 + hp8 * 16 + 8) = H1;
            *(ushort8_t*)(ldl + pb * 264 + hp8 * 16)     = L0;
            *(ushort8_t*)(ldl + pb * 264 + hp8 * 16 + 8) = L1;
        }
        __syncthreads();
        // MFMA: gates[16b x 128r] = d[16x256] @ Wslice^T  (hi*hi + lo*hi + hi*lo)
        floatx4 acc0 = {0.f, 0.f, 0.f, 0.f}, acc1 = {0.f, 0.f, 0.f, 0.f};
        #pragma unroll
        for (int kt = 0; kt < 8; ++kt) {
            short8 ah = *(const short8*)(ldh + n16 * 264 + kt * 32 + q * 8);
            short8 al = *(const short8*)(ldl + n16 * 264 + kt * 32 + q * 8);
            acc0 = __builtin_amdgcn_mfma_f32_16x16x32_bf16(ah, bfh[0][kt], acc0, 0, 0, 0);
            acc0 = __builtin_amdgcn_mfma_f32_16x16x32_bf16(al, bfh[0][kt], acc0, 0, 0, 0);
            acc0 = __builtin_amdgcn_mfma_f32_16x16x32_bf16(ah, bfl[0][kt], acc0, 0, 0, 0);
            acc1 = __builtin_amdgcn_mfma_f32_16x16x32_bf16(ah, bfh[1][kt], acc1, 0, 0, 0);
            acc1 = __builtin_amdgcn_mfma_f32_16x16x32_bf16(al, bfh[1][kt], acc1, 0, 0, 0);
            acc1 = __builtin_amdgcn_mfma_f32_16x16x32_bf16(ah, bfl[1][kt], acc1, 0, 0, 0);
        }
        #pragma unroll
        for (int reg = 0; reg < 4; ++reg) {
            gbuf[(q * 4 + reg) * 132 + (2 * w) * 16 + n16]     = acc0[reg];
            gbuf[(q * 4 + reg) * 132 + (2 * w + 1) * 16 + n16] = acc1[reg];
        }
        __syncthreads();
        // LSTM cell: 2 cells per thread
        float dnew[2];
        #pragma unroll
        for (int jj = 0; jj < 2; ++jj) {
            const int base = b_loc * 132 + (hloc0 + jj) * 4;
            float pi = gbuf[base + 0] + ytv * wihr[jj][0] + bihr[jj][0];
            float pf = gbuf[base + 1] + ytv * wihr[jj][1] + bihr[jj][1];
            float pg = gbuf[base + 2] + ytv * wihr[jj][2] + bihr[jj][2];
            float po = gbuf[base + 3] + ytv * wihr[jj][3] + bihr[jj][3];
            float ig = sigm_f(pi), fg = sigm_f(pf), og = sigm_f(po);
            float gg = tanh_f(pg);
            float& c = jj ? cc1 : cc0;
            c = fg * c + ig * gg;
            dnew[jj] = og * tanh_f(c);
        }
        if (t < T1) {
            const unsigned e = (unsigned)t & 3u;
            unsigned h0, l0, h1, l1;
            split_bf16(dnew[0], h0, l0);
            split_bf16(dnew[1], h1, l1);
            l0 = (l0 & 0xFFFEu) | (e & 1u);
            l1 = (l1 & 0xFFFEu) | ((e >> 1) & 1u);
            // own slice -> directly into next step's LDS slab
            *(ushort2*)(ldh + b_loc * 264 + hj * 32 + hloc0) =
                make_ushort2((ushort)h0, (ushort)h1);
            *(ushort2*)(ldl + b_loc * 264 + hj * 32 + hloc0) =
                make_ushort2((ushort)(l0 & 0xFFFEu), (ushort)(l1 & 0xFFFEu));
            unsigned long long wv = ((unsigned long long)h1 << 48) |
                                    ((unsigned long long)l1 << 32) |
                                    ((unsigned long long)h0 << 16) |
                                    (unsigned long long)l0;
            unsigned long long* Ddst = (t & 1) ? Dbuf1 : Dbuf0;
            unsigned long long* dstp = &Ddst[(size_t)bg * 128 + hj * 16 + hpair];
            // dual publish: plain store feeds the shared-L2 fast path...
            asm volatile("global_store_dwordx2 %0, %1, off"
                         :: "v"((unsigned long long)dstp), "v"(wv) : "memory");
            // ...agent-scope store feeds the IC fallback path
            __hip_atomic_store(dstp, wv, __ATOMIC_RELAXED, __HIP_MEMORY_SCOPE_AGENT);
        } else {
            *(float2*)(dT + bg * 256 + hj * 32 + hloc0) = make_float2(dnew[0], dnew[1]);
        }
    }
}

// ---------------- k_final: y_pred = W_final . [dT, context] + b ----------------
__global__ __launch_bounds__(256) void k_final(const float* __restrict__ W_final,
                                               const float* __restrict__ b_final,
                                               float* __restrict__ out,
                                               char* __restrict__ ws) {
    __shared__ float red[256];
    const int b = blockIdx.x, tid = threadIdx.x;
    const float* dT = (const float*)(ws + DT_OFF);
    const float* ctx = (const float*)(ws + CTX_OFF);
    float v = W_final[tid] * dT[b * 256 + tid] + W_final[256 + tid] * ctx[b * 256 + tid];
    red[tid] = v;
    __syncthreads();
    for (int s = 128; s >= 1; s >>= 1) { if (tid < s) red[tid] += red[tid + s]; __syncthreads(); }
    if (tid == 0) out[b] = red[0] + b_final[0];
}

extern "C" void kernel_launch(void* const* d_in, const int* in_sizes, int n_in,
                              void* d_out, int out_size, void* d_ws, size_t ws_size,
                              hipStream_t stream) {
    const float* X      = (const float*)d_in[0];
    const float* y_prev = (const float*)d_in[1];
    const float* W1     = (const float*)d_in[2];
    const float* W2     = (const float*)d_in[4];
    const float* W_fc   = (const float*)d_in[6];
    const float* b_fc   = (const float*)d_in[7];
    const float* W_ih   = (const float*)d_in[8];
    const float* W_hh   = (const float*)d_in[9];
    const float* b_ih   = (const float*)d_in[10];
    const float* b_hh   = (const float*)d_in[11];
    const float* W_fin  = (const float*)d_in[12];
    const float* b_fin  = (const float*)d_in[13];
    char* ws = (char*)d_ws;

    hipLaunchKernelGGL(k_prep,  dim3(256), dim3(256), 0, stream, W1, W2, W_hh, ws);
    hipLaunchKernelGGL(k_attn,  dim3(512), dim3(256), 0, stream, X, y_prev, W_fc, b_fc, ws);
    hipLaunchKernelGGL(k_lstm,  dim3(256), dim3(256), 0, stream, W_ih, b_ih, b_hh, ws);
    hipLaunchKernelGGL(k_final, dim3(512), dim3(256), 0, stream, W_fin, b_fin, (float*)d_out, ws);
}

// Round 8
// 1160.652 us; speedup vs baseline: 1.0287x; 1.0287x over previous
//
#include <hip/hip_runtime.h>
#include <stdint.h>

typedef __attribute__((ext_vector_type(8))) short short8;
typedef __attribute__((ext_vector_type(8))) unsigned short ushort8_t;
typedef __attribute__((ext_vector_type(4))) float floatx4;

#define T1 127
#define ENC 256
#define HD 256

// workspace offsets (bytes)
#define WHI_OFF   0u            // 1024*256 ushort = 524288
#define WLO_OFF   524288u
#define D0_OFF    1048576u      // 512*128 u64 = 524288  (epoch-tagged d words)
#define D1_OFF    1572864u
#define WEFF_OFF  2097152u      // 256 floats
#define YT_OFF    2099200u      // 512*128 fp32 = 262144
#define CTX_OFF   2361344u      // 512*256 fp32 = 524288
#define DT_OFF    2885632u      // 512*256 fp32 = 524288
#define CLAIM_OFF 3409920u      // [0..7] per-XCD cnt, [8] arrived, [9] overflow

__device__ __forceinline__ void split_bf16(float x, unsigned& hi, unsigned& lo) {
    unsigned u = __float_as_uint(x);
    hi = u >> 16;
    float hf = __uint_as_float(hi << 16);
    float r = x - hf;
    unsigned ur = __float_as_uint(r);
    lo = (ur + 0x7fffu + ((ur >> 16) & 1u)) >> 16;
}

__device__ __forceinline__ float sigm_f(float x) { return 1.f / (1.f + __expf(-x)); }
__device__ __forceinline__ float tanh_f(float x) {
    x = fminf(9.f, fmaxf(-9.f, x));
    float e = __expf(2.f * x);
    return (e - 1.f) / (e + 1.f);
}

// 64-byte line load, L1-bypass but L2-served (sc0 only) — the intra-XCD fast path.
__device__ __forceinline__ void load64_sc0(const unsigned long long* p,
                                           uint4& a, uint4& b, uint4& c, uint4& d) {
    asm volatile("global_load_dwordx4 %0, %4, off sc0\n\t"
                 "global_load_dwordx4 %1, %4, off offset:16 sc0\n\t"
                 "global_load_dwordx4 %2, %4, off offset:32 sc0\n\t"
                 "global_load_dwordx4 %3, %4, off offset:48 sc0\n\t"
                 "s_waitcnt vmcnt(0)"
                 : "=v"(a), "=v"(b), "=v"(c), "=v"(d)
                 : "v"((unsigned long long)p)
                 : "memory");
}

// ---------------- k_prep: weight collapse + W_hh hi/lo split + init ----------------
__global__ __launch_bounds__(256) void k_prep(const float* __restrict__ W1,
                                              const float* __restrict__ W2,
                                              const float* __restrict__ W_hh,
                                              char* __restrict__ ws) {
    const int tid = threadIdx.x, bid = blockIdx.x;
    ushort* Whi = (ushort*)(ws + WHI_OFF);
    ushort* Wlo = (ushort*)(ws + WLO_OFF);
    {
        const int i4 = bid * 256 + tid;   // 0..65535
        float4 v = ((const float4*)W_hh)[i4];
        float vv[4] = {v.x, v.y, v.z, v.w};
        unsigned h[4], l[4];
        #pragma unroll
        for (int j = 0; j < 4; ++j) split_bf16(vv[j], h[j], l[j]);
        *(ushort4*)(Whi + i4 * 4) = make_ushort4((ushort)h[0], (ushort)h[1], (ushort)h[2], (ushort)h[3]);
        *(ushort4*)(Wlo + i4 * 4) = make_ushort4((ushort)l[0], (ushort)l[1], (ushort)l[2], (ushort)l[3]);
    }
    {
        const int idx = bid * 256 + tid;
        if (idx < 32768) ((uint4*)(ws + D0_OFF))[idx] = make_uint4(0, 0, 0, 0);
    }
    if (bid == 2 && tid < 16) ((unsigned*)(ws + CLAIM_OFF))[tid] = 0u;
    if (bid == 0) {
        float acc = 0.f;
        for (int j = 0; j < 128; ++j)
            acc = fmaf(W2[j], W1[j * 768 + 512 + tid], acc);
        ((float*)(ws + WEFF_OFF))[tid] = acc;
    }
}

// ---------------- k_attn: scores -> softmax -> context -> y_tilde ----------------
__global__ __launch_bounds__(256) void k_attn(const float* __restrict__ X,
                                              const float* __restrict__ y_prev,
                                              const float* __restrict__ W_fc,
                                              const float* __restrict__ b_fc,
                                              char* __restrict__ ws) {
    __shared__ float s_lds[128];
    __shared__ float beta[128];
    __shared__ float red[256];
    const int b = blockIdx.x, tid = threadIdx.x;
    const int w = tid >> 6, lane = tid & 63;
    const float* Xb = X + (size_t)b * T1 * ENC;
    const float* weff = (const float*)(ws + WEFF_OFF);
    const float4 w4 = ((const float4*)weff)[lane];
    for (int i = 0; i < 32; ++i) {
        int t = w * 32 + i;
        if (t >= T1) break;
        float4 x4 = ((const float4*)(Xb + t * ENC))[lane];
        float a = x4.x * w4.x + x4.y * w4.y + x4.z * w4.z + x4.w * w4.w;
        for (int m = 32; m >= 1; m >>= 1) a += __shfl_xor(a, m, 64);
        if (lane == 0) s_lds[t] = a;
    }
    __syncthreads();
    if (w == 0) {
        float v0 = s_lds[lane];
        float v1 = (lane + 64 < T1) ? s_lds[lane + 64] : -1e30f;
        float mx = fmaxf(v0, v1);
        for (int m = 32; m >= 1; m >>= 1) mx = fmaxf(mx, __shfl_xor(mx, m, 64));
        float e0 = __expf(v0 - mx);
        float e1 = (lane + 64 < T1) ? __expf(v1 - mx) : 0.f;
        float s = e0 + e1;
        for (int m = 32; m >= 1; m >>= 1) s += __shfl_xor(s, m, 64);
        float inv = 1.f / s;
        beta[lane] = e0 * inv;
        if (lane + 64 < T1) beta[lane + 64] = e1 * inv;
    }
    __syncthreads();
    float acc = 0.f;
    for (int t = 0; t < T1; ++t) acc = fmaf(beta[t], Xb[t * ENC + tid], acc);
    ((float*)(ws + CTX_OFF))[b * ENC + tid] = acc;
    red[tid] = acc * W_fc[tid];
    __syncthreads();
    for (int s = 128; s >= 1; s >>= 1) { if (tid < s) red[tid] += red[tid + s]; __syncthreads(); }
    const float u = red[0] + b_fc[0];
    const float wy = W_fc[256];
    if (tid < T1)
        ((float*)(ws + YT_OFF))[b * 128 + tid] = u + wy * y_prev[b * T1 + tid];
}

// ---------------- k_lstm: persistent LSTM, runtime-XCD groups + hybrid L2/IC poll ----------------
// Each block reads its physical XCD (s_getreg HW_REG_XCC_ID) and claims a slot via a
// per-XCD counter: groups of 8 blocks are same-XCD BY CONSTRUCTION, so producers' plain
// stores and consumers' sc0 polls meet in the shared intra-XCD L2. Overflow blocks take
// deterministic leftover slots (correct, IC-speed). Poll is hybrid and never sticky:
// 3 cheap sc0 rounds, then agent-scope (IC) stale-only rounds — the R5-proven path.
__global__ __launch_bounds__(256, 1) void k_lstm(const float* __restrict__ W_ih,
                                                 const float* __restrict__ b_ih,
                                                 const float* __restrict__ b_hh,
                                                 char* __restrict__ ws) {
    __shared__ __align__(16) ushort ldh[16 * 264];
    __shared__ __align__(16) ushort ldl[16 * 264];
    __shared__ float gbuf[16 * 132];
    __shared__ int s_slot;

    const int tid = threadIdx.x;

    // ---- claim a (gi,hj) slot on this block's physical XCD ----
    if (tid == 0) {
        unsigned* cl = (unsigned*)(ws + CLAIM_OFF);
        // hwreg(id=20 XCC_ID, offset=0, width=4): imm = 20 | (0<<6) | ((4-1)<<11)
        unsigned xcc = __builtin_amdgcn_s_getreg(20 | (3 << 11)) & 7u;
        unsigned my = atomicAdd(&cl[xcc], 1u);
        int slot;
        if (my < 32u) {
            slot = (int)(xcc * 32u + my);
            atomicAdd(&cl[8], 1u);
        } else {
            unsigned ovr = atomicAdd(&cl[9], 1u);
            atomicAdd(&cl[8], 1u);
            while (__hip_atomic_load(&cl[8], __ATOMIC_RELAXED, __HIP_MEMORY_SCOPE_AGENT) < 256u)
                __builtin_amdgcn_s_sleep(8);
            unsigned cnt[8];
            #pragma unroll
            for (int x = 0; x < 8; ++x) {
                unsigned c = __hip_atomic_load(&cl[x], __ATOMIC_RELAXED, __HIP_MEMORY_SCOPE_AGENT);
                cnt[x] = c < 32u ? c : 32u;
            }
            int r = (int)ovr; slot = -1;
            for (int x = 0; x < 8 && slot < 0; ++x)
                for (unsigned i = cnt[x]; i < 32u; ++i) {
                    if (r == 0) { slot = x * 32 + (int)i; break; }
                    --r;
                }
        }
        s_slot = slot;
    }
    __syncthreads();
    const int gi = s_slot >> 3, hj = s_slot & 7;

    const int w = tid >> 6, lane = tid & 63;
    const int n16 = lane & 15, q = lane >> 4;

    const ushort* Whi = (const ushort*)(ws + WHI_OFF);
    const ushort* Wlo = (const ushort*)(ws + WLO_OFF);
    unsigned long long* Dbuf0 = (unsigned long long*)(ws + D0_OFF);
    unsigned long long* Dbuf1 = (unsigned long long*)(ws + D1_OFF);
    const float* yt = (const float*)(ws + YT_OFF);
    float* dT = (float*)(ws + DT_OFF);

    // resident W fragments: wave w owns N-tiles {2w, 2w+1}; row r = hloc*4 + g
    short8 bfh[2][8], bfl[2][8];
    #pragma unroll
    for (int j = 0; j < 2; ++j) {
        const int r = (2 * w + j) * 16 + n16;          // 0..127
        const int hloc = r >> 2, g = r & 3;
        const int R = g * 256 + hj * 32 + hloc;        // global gate row
        #pragma unroll
        for (int kt = 0; kt < 8; ++kt) {
            bfh[j][kt] = *(const short8*)(Whi + R * 256 + kt * 32 + q * 8);
            bfl[j][kt] = *(const short8*)(Wlo + R * 256 + kt * 32 + q * 8);
        }
    }

    // cell assignment: 16 batches x 32 h = 512 cells, 2 per thread
    const int b_loc = tid & 15, hpair = tid >> 4;      // hpair 0..15
    const int hloc0 = hpair * 2;
    const int bg = gi * 16 + b_loc;
    float wihr[2][4], bihr[2][4];
    #pragma unroll
    for (int jj = 0; jj < 2; ++jj)
        #pragma unroll
        for (int g = 0; g < 4; ++g) {
            const int row = g * HD + hj * 32 + hloc0 + jj;
            wihr[jj][g] = W_ih[row];
            bihr[jj][g] = b_ih[row] + b_hh[row];
        }
    float cc0 = 0.f, cc1 = 0.f;

    // poll/stage assignment: thread covers batch pb = tid>>4, hp8 = tid&15
    const int pb = tid >> 4, hp8 = tid & 15;
    const bool own = ((hp8 >> 1) == hj);
    const size_t pbase = (size_t)(gi * 16 + pb) * 128 + hp8 * 8;

    {
        ushort8_t z = {0, 0, 0, 0, 0, 0, 0, 0};
        *(ushort8_t*)(ldh + pb * 264 + hp8 * 16)     = z;
        *(ushort8_t*)(ldh + pb * 264 + hp8 * 16 + 8) = z;
        *(ushort8_t*)(ldl + pb * 264 + hp8 * 16)     = z;
        *(ushort8_t*)(ldl + pb * 264 + hp8 * 16 + 8) = z;
    }

    for (int t = 1; t <= T1; ++t) {
        const float ytv = yt[bg * 128 + (t - 1)];   // prefetch, independent of d
        if (!own) {
            unsigned long long* Dsrc = ((t - 1) & 1) ? Dbuf1 : Dbuf0;
            const unsigned e = (unsigned)(t - 1) & 3u;
            unsigned lo[8], hi[8];
            unsigned stale = 0xFFu;
            for (int round = 0; ; ++round) {
                if (round < 3) {
                    // cheap same-XCD path: one 64B sc0 line load (L2-served)
                    uint4 A, B, C, D;
                    load64_sc0(&Dsrc[pbase], A, B, C, D);
                    lo[0] = A.x; hi[0] = A.y; lo[1] = A.z; hi[1] = A.w;
                    lo[2] = B.x; hi[2] = B.y; lo[3] = B.z; hi[3] = B.w;
                    lo[4] = C.x; hi[4] = C.y; lo[5] = C.z; hi[5] = C.w;
                    lo[6] = D.x; hi[6] = D.y; lo[7] = D.z; hi[7] = D.w;
                } else {
                    // guaranteed path: agent-scope (IC) stale-only reload
                    #pragma unroll
                    for (int i = 0; i < 8; ++i)
                        if (stale & (1u << i)) {
                            unsigned long long wv =
                                __hip_atomic_load(&Dsrc[pbase + i], __ATOMIC_RELAXED,
                                                  __HIP_MEMORY_SCOPE_AGENT);
                            lo[i] = (unsigned)wv; hi[i] = (unsigned)(wv >> 32);
                        }
                }
                unsigned ns = 0;
                #pragma unroll
                for (int i = 0; i < 8; ++i) {
                    unsigned ep = (lo[i] & 1u) | ((hi[i] & 1u) << 1);
                    if (ep != e) ns |= 1u << i;
                }
                if (!ns) break;
                stale = ns;
                if (round >= 1) __builtin_amdgcn_s_sleep(1);
            }
            // decode: 16 hi + 16 lo ushorts -> two b128 stores per plane
            ushort hv[16], lv[16];
            #pragma unroll
            for (int i = 0; i < 8; ++i) {
                hv[2 * i]     = (ushort)(lo[i] >> 16);
                hv[2 * i + 1] = (ushort)(hi[i] >> 16);
                lv[2 * i]     = (ushort)(lo[i] & 0xFFFEu);
                lv[2 * i + 1] = (ushort)(hi[i] & 0xFFFEu);
            }
            ushort8_t H0, L0, H1, L1;
            #pragma unroll
            for (int i = 0; i < 8; ++i) { H0[i] = hv[i]; L0[i] = lv[i]; H1[i] = hv[8 + i]; L1[i] = lv[8 + i]; }
            *(ushort8_t*)(ldh + pb * 264 + hp8 * 16)     = H0;
            *(ushort8_t*)(ldh + pb * 264 + hp8 * 16 + 8) = H1;
            *(ushort8_t*)(ldl + pb * 264 + hp8 * 16)     = L0;
            *(ushort8_t*)(ldl + pb * 264 + hp8 * 16 + 8) = L1;
        }
        __syncthreads();
        // MFMA: gates[16b x 128r] = d[16x256] @ Wslice^T  (hi*hi + lo*hi + hi*lo)
        floatx4 acc0 = {0.f, 0.f, 0.f, 0.f}, acc1 = {0.f, 0.f, 0.f, 0.f};
        #pragma unroll
        for (int kt = 0; kt < 8; ++kt) {
            short8 ah = *(const short8*)(ldh + n16 * 264 + kt * 32 + q * 8);
            short8 al = *(const short8*)(ldl + n16 * 264 + kt * 32 + q * 8);
            acc0 = __builtin_amdgcn_mfma_f32_16x16x32_bf16(ah, bfh[0][kt], acc0, 0, 0, 0);
            acc0 = __builtin_amdgcn_mfma_f32_16x16x32_bf16(al, bfh[0][kt], acc0, 0, 0, 0);
            acc0 = __builtin_amdgcn_mfma_f32_16x16x32_bf16(ah, bfl[0][kt], acc0, 0, 0, 0);
            acc1 = __builtin_amdgcn_mfma_f32_16x16x32_bf16(ah, bfh[1][kt], acc1, 0, 0, 0);
            acc1 = __builtin_amdgcn_mfma_f32_16x16x32_bf16(al, bfh[1][kt], acc1, 0, 0, 0);
            acc1 = __builtin_amdgcn_mfma_f32_16x16x32_bf16(ah, bfl[1][kt], acc1, 0, 0, 0);
        }
        #pragma unroll
        for (int reg = 0; reg < 4; ++reg) {
            gbuf[(q * 4 + reg) * 132 + (2 * w) * 16 + n16]     = acc0[reg];
            gbuf[(q * 4 + reg) * 132 + (2 * w + 1) * 16 + n16] = acc1[reg];
        }
        __syncthreads();
        // LSTM cell: 2 cells per thread
        float dnew[2];
        #pragma unroll
        for (int jj = 0; jj < 2; ++jj) {
            const int base = b_loc * 132 + (hloc0 + jj) * 4;
            float pi = gbuf[base + 0] + ytv * wihr[jj][0] + bihr[jj][0];
            float pf = gbuf[base + 1] + ytv * wihr[jj][1] + bihr[jj][1];
            float pg = gbuf[base + 2] + ytv * wihr[jj][2] + bihr[jj][2];
            float po = gbuf[base + 3] + ytv * wihr[jj][3] + bihr[jj][3];
            float ig = sigm_f(pi), fg = sigm_f(pf), og = sigm_f(po);
            float gg = tanh_f(pg);
            float& c = jj ? cc1 : cc0;
            c = fg * c + ig * gg;
            dnew[jj] = og * tanh_f(c);
        }
        if (t < T1) {
            const unsigned e = (unsigned)t & 3u;
            unsigned h0, l0, h1, l1;
            split_bf16(dnew[0], h0, l0);
            split_bf16(dnew[1], h1, l1);
            l0 = (l0 & 0xFFFEu) | (e & 1u);
            l1 = (l1 & 0xFFFEu) | ((e >> 1) & 1u);
            // own slice -> directly into next step's LDS slab
            *(ushort2*)(ldh + b_loc * 264 + hj * 32 + hloc0) =
                make_ushort2((ushort)h0, (ushort)h1);
            *(ushort2*)(ldl + b_loc * 264 + hj * 32 + hloc0) =
                make_ushort2((ushort)(l0 & 0xFFFEu), (ushort)(l1 & 0xFFFEu));
            unsigned long long wv = ((unsigned long long)h1 << 48) |
                                    ((unsigned long long)l1 << 32) |
                                    ((unsigned long long)h0 << 16) |
                                    (unsigned long long)l0;
            unsigned long long* Ddst = (t & 1) ? Dbuf1 : Dbuf0;
            unsigned long long* dstp = &Ddst[(size_t)bg * 128 + hj * 16 + hpair];
            // dual publish: plain store feeds the same-XCD L2 fast path...
            asm volatile("global_store_dwordx2 %0, %1, off"
                         :: "v"((unsigned long long)dstp), "v"(wv) : "memory");
            // ...agent-scope store feeds the IC fallback path
            __hip_atomic_store(dstp, wv, __ATOMIC_RELAXED, __HIP_MEMORY_SCOPE_AGENT);
        } else {
            *(float2*)(dT + bg * 256 + hj * 32 + hloc0) = make_float2(dnew[0], dnew[1]);
        }
    }
}

// ---------------- k_final: y_pred = W_final . [dT, context] + b ----------------
__global__ __launch_bounds__(256) void k_final(const float* __restrict__ W_final,
                                               const float* __restrict__ b_final,
                                               float* __restrict__ out,
                                               char* __restrict__ ws) {
    __shared__ float red[256];
    const int b = blockIdx.x, tid = threadIdx.x;
    const float* dT = (const float*)(ws + DT_OFF);
    const float* ctx = (const float*)(ws + CTX_OFF);
    float v = W_final[tid] * dT[b * 256 + tid] + W_final[256 + tid] * ctx[b * 256 + tid];
    red[tid] = v;
    __syncthreads();
    for (int s = 128; s >= 1; s >>= 1) { if (tid < s) red[tid] += red[tid + s]; __syncthreads(); }
    if (tid == 0) out[b] = red[0] + b_final[0];
}

extern "C" void kernel_launch(void* const* d_in, const int* in_sizes, int n_in,
                              void* d_out, int out_size, void* d_ws, size_t ws_size,
                              hipStream_t stream) {
    const float* X      = (const float*)d_in[0];
    const float* y_prev = (const float*)d_in[1];
    const float* W1     = (const float*)d_in[2];
    const float* W2     = (const float*)d_in[4];
    const float* W_fc   = (const float*)d_in[6];
    const float* b_fc   = (const float*)d_in[7];
    const float* W_ih   = (const float*)d_in[8];
    const float* W_hh   = (const float*)d_in[9];
    const float* b_ih   = (const float*)d_in[10];
    const float* b_hh   = (const float*)d_in[11];
    const float* W_fin  = (const float*)d_in[12];
    const float* b_fin  = (const float*)d_in[13];
    char* ws = (char*)d_ws;

    hipLaunchKernelGGL(k_prep,  dim3(256), dim3(256), 0, stream, W1, W2, W_hh, ws);
    hipLaunchKernelGGL(k_attn,  dim3(512), dim3(256), 0, stream, X, y_prev, W_fc, b_fc, ws);
    hipLaunchKernelGGL(k_lstm,  dim3(256), dim3(256), 0, stream, W_ih, b_ih, b_hh, ws);
    hipLaunchKernelGGL(k_final, dim3(512), dim3(256), 0, stream, W_fin, b_fin, (float*)d_out, ws);
}

// Round 9
// 831.092 us; speedup vs baseline: 1.4366x; 1.3965x over previous
//
#include <hip/hip_runtime.h>
#include <stdint.h>

typedef __attribute__((ext_vector_type(8))) short short8;
typedef __attribute__((ext_vector_type(8))) unsigned short ushort8_t;
typedef __attribute__((ext_vector_type(4))) float floatx4;

#define T1 127
#define ENC 256
#define HD 256

// workspace offsets (bytes)
#define WHI_OFF   0u            // 1024*256 ushort = 524288
#define WLO_OFF   524288u
#define D0_OFF    1048576u      // 512*128 u64 = 524288  (epoch-tagged d words)
#define D1_OFF    1572864u
#define WEFF_OFF  2097152u      // 256 floats
#define YT_OFF    2099200u      // 512*128 fp32 = 262144
#define CTX_OFF   2361344u      // 512*256 fp32 = 524288
#define DT_OFF    2885632u      // 512*256 fp32 = 524288

__device__ __forceinline__ void split_bf16(float x, unsigned& hi, unsigned& lo) {
    unsigned u = __float_as_uint(x);
    hi = u >> 16;
    float hf = __uint_as_float(hi << 16);
    float r = x - hf;
    unsigned ur = __float_as_uint(r);
    lo = (ur + 0x7fffu + ((ur >> 16) & 1u)) >> 16;
}

__device__ __forceinline__ float sigm_f(float x) { return 1.f / (1.f + __expf(-x)); }
__device__ __forceinline__ float tanh_f(float x) {
    x = fminf(9.f, fmaxf(-9.f, x));
    float e = __expf(2.f * x);
    return (e - 1.f) / (e + 1.f);
}

// ---------------- k_prep: weight collapse + W_hh hi/lo split + init ----------------
__global__ __launch_bounds__(256) void k_prep(const float* __restrict__ W1,
                                              const float* __restrict__ W2,
                                              const float* __restrict__ W_hh,
                                              char* __restrict__ ws) {
    const int tid = threadIdx.x, bid = blockIdx.x;
    ushort* Whi = (ushort*)(ws + WHI_OFF);
    ushort* Wlo = (ushort*)(ws + WLO_OFF);
    {
        const int i4 = bid * 256 + tid;   // 0..65535
        float4 v = ((const float4*)W_hh)[i4];
        float vv[4] = {v.x, v.y, v.z, v.w};
        unsigned h[4], l[4];
        #pragma unroll
        for (int j = 0; j < 4; ++j) split_bf16(vv[j], h[j], l[j]);
        *(ushort4*)(Whi + i4 * 4) = make_ushort4((ushort)h[0], (ushort)h[1], (ushort)h[2], (ushort)h[3]);
        *(ushort4*)(Wlo + i4 * 4) = make_ushort4((ushort)l[0], (ushort)l[1], (ushort)l[2], (ushort)l[3]);
    }
    {
        const int idx = bid * 256 + tid;
        if (idx < 32768) ((uint4*)(ws + D0_OFF))[idx] = make_uint4(0, 0, 0, 0);
    }
    if (bid == 0) {
        float acc = 0.f;
        for (int j = 0; j < 128; ++j)
            acc = fmaf(W2[j], W1[j * 768 + 512 + tid], acc);
        ((float*)(ws + WEFF_OFF))[tid] = acc;
    }
}

// ---------------- k_attn: scores -> softmax -> context -> y_tilde ----------------
__global__ __launch_bounds__(256) void k_attn(const float* __restrict__ X,
                                              const float* __restrict__ y_prev,
                                              const float* __restrict__ W_fc,
                                              const float* __restrict__ b_fc,
                                              char* __restrict__ ws) {
    __shared__ float s_lds[128];
    __shared__ float beta[128];
    __shared__ float red[256];
    const int b = blockIdx.x, tid = threadIdx.x;
    const int w = tid >> 6, lane = tid & 63;
    const float* Xb = X + (size_t)b * T1 * ENC;
    const float* weff = (const float*)(ws + WEFF_OFF);
    const float4 w4 = ((const float4*)weff)[lane];
    for (int i = 0; i < 32; ++i) {
        int t = w * 32 + i;
        if (t >= T1) break;
        float4 x4 = ((const float4*)(Xb + t * ENC))[lane];
        float a = x4.x * w4.x + x4.y * w4.y + x4.z * w4.z + x4.w * w4.w;
        for (int m = 32; m >= 1; m >>= 1) a += __shfl_xor(a, m, 64);
        if (lane == 0) s_lds[t] = a;
    }
    __syncthreads();
    if (w == 0) {
        float v0 = s_lds[lane];
        float v1 = (lane + 64 < T1) ? s_lds[lane + 64] : -1e30f;
        float mx = fmaxf(v0, v1);
        for (int m = 32; m >= 1; m >>= 1) mx = fmaxf(mx, __shfl_xor(mx, m, 64));
        float e0 = __expf(v0 - mx);
        float e1 = (lane + 64 < T1) ? __expf(v1 - mx) : 0.f;
        float s = e0 + e1;
        for (int m = 32; m >= 1; m >>= 1) s += __shfl_xor(s, m, 64);
        float inv = 1.f / s;
        beta[lane] = e0 * inv;
        if (lane + 64 < T1) beta[lane + 64] = e1 * inv;
    }
    __syncthreads();
    float acc = 0.f;
    for (int t = 0; t < T1; ++t) acc = fmaf(beta[t], Xb[t * ENC + tid], acc);
    ((float*)(ws + CTX_OFF))[b * ENC + tid] = acc;
    red[tid] = acc * W_fc[tid];
    __syncthreads();
    for (int s = 128; s >= 1; s >>= 1) { if (tid < s) red[tid] += red[tid + s]; __syncthreads(); }
    const float u = red[0] + b_fc[0];
    const float wy = W_fc[256];
    if (tid < T1)
        ((float*)(ws + YT_OFF))[b * 128 + tid] = u + wy * y_prev[b * T1 + tid];
}

// ---------------- k_lstm: persistent LSTM, R5 IC protocol + 2-way set interleave ----------------
// 128 blocks: hj = bk&7 (h-slice, W regs shared), pi = bk>>3 (0..15). Block handles
// batch-sets {2pi, 2pi+1} (16 batches each), alternating per step: while set A's
// publish propagates through the Infinity Cache, the block computes set B.
// Exchange: R5-proven epoch-in-data u64 agent-scope stores + stale-only polls.
// Per-set LDS d-slabs keep the own-slice LDS bypass alive.
__global__ __launch_bounds__(256, 1) void k_lstm(const float* __restrict__ W_ih,
                                                 const float* __restrict__ b_ih,
                                                 const float* __restrict__ b_hh,
                                                 char* __restrict__ ws) {
    __shared__ __align__(16) ushort ldh[2][4224];   // [set][16*264]
    __shared__ __align__(16) ushort ldl[2][4224];
    __shared__ float gbuf[16 * 132];                // shared, transient per process

    const int tid = threadIdx.x, bk = blockIdx.x;
    const int hj = bk & 7, pi = bk >> 3;
    const int w = tid >> 6, lane = tid & 63;
    const int n16 = lane & 15, q = lane >> 4;

    const ushort* Whi = (const ushort*)(ws + WHI_OFF);
    const ushort* Wlo = (const ushort*)(ws + WLO_OFF);
    unsigned long long* Dbuf0 = (unsigned long long*)(ws + D0_OFF);
    unsigned long long* Dbuf1 = (unsigned long long*)(ws + D1_OFF);
    const float* yt = (const float*)(ws + YT_OFF);
    float* dT = (float*)(ws + DT_OFF);

    // resident W fragments (hj slice, shared by both sets): wave w owns N-tiles {2w,2w+1}
    short8 bfh[2][8], bfl[2][8];
    #pragma unroll
    for (int j = 0; j < 2; ++j) {
        const int r = (2 * w + j) * 16 + n16;          // 0..127
        const int hloc = r >> 2, g = r & 3;
        const int R = g * 256 + hj * 32 + hloc;        // global gate row
        #pragma unroll
        for (int kt = 0; kt < 8; ++kt) {
            bfh[j][kt] = *(const short8*)(Whi + R * 256 + kt * 32 + q * 8);
            bfl[j][kt] = *(const short8*)(Wlo + R * 256 + kt * 32 + q * 8);
        }
    }

    // cell assignment: per set, 16 batches x 32 h = 512 cells, 2 per thread
    const int b_loc = tid & 15, hpair = tid >> 4;      // hpair 0..15
    const int hloc0 = hpair * 2;
    const int bgs[2] = { (2 * pi) * 16 + b_loc, (2 * pi + 1) * 16 + b_loc };
    float wihr[2][4], bihr[2][4];                      // h-dependent only: shared by sets
    #pragma unroll
    for (int jj = 0; jj < 2; ++jj)
        #pragma unroll
        for (int g = 0; g < 4; ++g) {
            const int row = g * HD + hj * 32 + hloc0 + jj;
            wihr[jj][g] = W_ih[row];
            bihr[jj][g] = b_ih[row] + b_hh[row];
        }
    float cc[2][2] = {{0.f, 0.f}, {0.f, 0.f}};

    // poll/stage assignment: thread covers batch pb, word-octet hp8; origin block hp8>>1
    const int pb = tid >> 4, hp8 = tid & 15;
    const bool own = ((hp8 >> 1) == hj);
    const size_t pbases[2] = {
        ((size_t)((2 * pi) * 16 + pb)) * 128 + hp8 * 8,
        ((size_t)((2 * pi + 1) * 16 + pb)) * 128 + hp8 * 8
    };

    // pre-zero both sets' slab segments (d0 = 0), both halves, both planes
    {
        ushort8_t z = {0, 0, 0, 0, 0, 0, 0, 0};
        #pragma unroll
        for (int s = 0; s < 2; ++s) {
            *(ushort8_t*)(&ldh[s][pb * 264 + hp8 * 16])     = z;
            *(ushort8_t*)(&ldh[s][pb * 264 + hp8 * 16 + 8]) = z;
            *(ushort8_t*)(&ldl[s][pb * 264 + hp8 * 16])     = z;
            *(ushort8_t*)(&ldl[s][pb * 264 + hp8 * 16 + 8]) = z;
        }
    }

    for (int t = 1; t <= T1; ++t) {
        #pragma unroll
        for (int s = 0; s < 2; ++s) {
            const int bg = bgs[s];
            const float ytv = yt[bg * 128 + (t - 1)];
            // ---- poll d_{t-1} for this set (agent/IC, stale-only reload) ----
            if (!own) {
                unsigned long long* Dsrc = ((t - 1) & 1) ? Dbuf1 : Dbuf0;
                const unsigned e = (unsigned)(t - 1) & 3u;
                const size_t pbase = pbases[s];
                unsigned long long wv[8];
                #pragma unroll
                for (int i = 0; i < 8; ++i)
                    wv[i] = __hip_atomic_load(&Dsrc[pbase + i], __ATOMIC_RELAXED,
                                              __HIP_MEMORY_SCOPE_AGENT);
                unsigned stale = 0xFFu;
                for (int round = 0; ; ++round) {
                    unsigned ns = 0;
                    #pragma unroll
                    for (int i = 0; i < 8; ++i)
                        if (stale & (1u << i)) {
                            unsigned ep = (unsigned)(wv[i] & 1ull) |
                                          (((unsigned)(wv[i] >> 32) & 1u) << 1);
                            if (ep != e) ns |= 1u << i;
                        }
                    if (!ns) break;
                    if (round >= 2) __builtin_amdgcn_s_sleep(1);
                    #pragma unroll
                    for (int i = 0; i < 8; ++i)
                        if (ns & (1u << i))
                            wv[i] = __hip_atomic_load(&Dsrc[pbase + i], __ATOMIC_RELAXED,
                                                      __HIP_MEMORY_SCOPE_AGENT);
                    stale = ns;
                }
                // decode into this set's slab
                ushort hv[16], lv[16];
                #pragma unroll
                for (int i = 0; i < 8; ++i) {
                    hv[2 * i]     = (ushort)((wv[i] >> 16) & 0xFFFFull);
                    hv[2 * i + 1] = (ushort)(wv[i] >> 48);
                    lv[2 * i]     = (ushort)(wv[i] & 0xFFFEull);
                    lv[2 * i + 1] = (ushort)((wv[i] >> 32) & 0xFFFEull);
                }
                ushort8_t H0, L0, H1, L1;
                #pragma unroll
                for (int i = 0; i < 8; ++i) { H0[i] = hv[i]; L0[i] = lv[i]; H1[i] = hv[8 + i]; L1[i] = lv[8 + i]; }
                *(ushort8_t*)(&ldh[s][pb * 264 + hp8 * 16])     = H0;
                *(ushort8_t*)(&ldh[s][pb * 264 + hp8 * 16 + 8]) = H1;
                *(ushort8_t*)(&ldl[s][pb * 264 + hp8 * 16])     = L0;
                *(ushort8_t*)(&ldl[s][pb * 264 + hp8 * 16 + 8]) = L1;
            }
            __syncthreads();
            // MFMA: gates[16b x 128r] = d[16x256] @ Wslice^T  (hi*hi + lo*hi + hi*lo)
            floatx4 acc0 = {0.f, 0.f, 0.f, 0.f}, acc1 = {0.f, 0.f, 0.f, 0.f};
            #pragma unroll
            for (int kt = 0; kt < 8; ++kt) {
                short8 ah = *(const short8*)(&ldh[s][n16 * 264 + kt * 32 + q * 8]);
                short8 al = *(const short8*)(&ldl[s][n16 * 264 + kt * 32 + q * 8]);
                acc0 = __builtin_amdgcn_mfma_f32_16x16x32_bf16(ah, bfh[0][kt], acc0, 0, 0, 0);
                acc0 = __builtin_amdgcn_mfma_f32_16x16x32_bf16(al, bfh[0][kt], acc0, 0, 0, 0);
                acc0 = __builtin_amdgcn_mfma_f32_16x16x32_bf16(ah, bfl[0][kt], acc0, 0, 0, 0);
                acc1 = __builtin_amdgcn_mfma_f32_16x16x32_bf16(ah, bfh[1][kt], acc1, 0, 0, 0);
                acc1 = __builtin_amdgcn_mfma_f32_16x16x32_bf16(al, bfh[1][kt], acc1, 0, 0, 0);
                acc1 = __builtin_amdgcn_mfma_f32_16x16x32_bf16(ah, bfl[1][kt], acc1, 0, 0, 0);
            }
            #pragma unroll
            for (int reg = 0; reg < 4; ++reg) {
                gbuf[(q * 4 + reg) * 132 + (2 * w) * 16 + n16]     = acc0[reg];
                gbuf[(q * 4 + reg) * 132 + (2 * w + 1) * 16 + n16] = acc1[reg];
            }
            __syncthreads();
            // LSTM cell: 2 cells per thread
            float dnew[2];
            #pragma unroll
            for (int jj = 0; jj < 2; ++jj) {
                const int base = b_loc * 132 + (hloc0 + jj) * 4;
                float pi_ = gbuf[base + 0] + ytv * wihr[jj][0] + bihr[jj][0];
                float pf  = gbuf[base + 1] + ytv * wihr[jj][1] + bihr[jj][1];
                float pg  = gbuf[base + 2] + ytv * wihr[jj][2] + bihr[jj][2];
                float po  = gbuf[base + 3] + ytv * wihr[jj][3] + bihr[jj][3];
                float ig = sigm_f(pi_), fg = sigm_f(pf), og = sigm_f(po);
                float gg = tanh_f(pg);
                float& c = cc[s][jj];
                c = fg * c + ig * gg;
                dnew[jj] = og * tanh_f(c);
            }
            if (t < T1) {
                const unsigned e = (unsigned)t & 3u;
                unsigned h0, l0, h1, l1;
                split_bf16(dnew[0], h0, l0);
                split_bf16(dnew[1], h1, l1);
                l0 = (l0 & 0xFFFEu) | (e & 1u);
                l1 = (l1 & 0xFFFEu) | ((e >> 1) & 1u);
                // own slice -> directly into this set's next-step LDS slab
                *(ushort2*)(&ldh[s][b_loc * 264 + hj * 32 + hloc0]) =
                    make_ushort2((ushort)h0, (ushort)h1);
                *(ushort2*)(&ldl[s][b_loc * 264 + hj * 32 + hloc0]) =
                    make_ushort2((ushort)(l0 & 0xFFFEu), (ushort)(l1 & 0xFFFEu));
                // publish for the other 7 blocks (single agent-scope store, R5 protocol)
                unsigned long long wv = ((unsigned long long)h1 << 48) |
                                        ((unsigned long long)l1 << 32) |
                                        ((unsigned long long)h0 << 16) |
                                        (unsigned long long)l0;
                unsigned long long* Ddst = (t & 1) ? Dbuf1 : Dbuf0;
                __hip_atomic_store(&Ddst[(size_t)bg * 128 + hj * 16 + hpair], wv,
                                   __ATOMIC_RELAXED, __HIP_MEMORY_SCOPE_AGENT);
            } else {
                *(float2*)(dT + bg * 256 + hj * 32 + hloc0) = make_float2(dnew[0], dnew[1]);
            }
        }
    }
}

// ---------------- k_final: y_pred = W_final . [dT, context] + b ----------------
__global__ __launch_bounds__(256) void k_final(const float* __restrict__ W_final,
                                               const float* __restrict__ b_final,
                                               float* __restrict__ out,
                                               char* __restrict__ ws) {
    __shared__ float red[256];
    const int b = blockIdx.x, tid = threadIdx.x;
    const float* dT = (const float*)(ws + DT_OFF);
    const float* ctx = (const float*)(ws + CTX_OFF);
    float v = W_final[tid] * dT[b * 256 + tid] + W_final[256 + tid] * ctx[b * 256 + tid];
    red[tid] = v;
    __syncthreads();
    for (int s = 128; s >= 1; s >>= 1) { if (tid < s) red[tid] += red[tid + s]; __syncthreads(); }
    if (tid == 0) out[b] = red[0] + b_final[0];
}

extern "C" void kernel_launch(void* const* d_in, const int* in_sizes, int n_in,
                              void* d_out, int out_size, void* d_ws, size_t ws_size,
                              hipStream_t stream) {
    const float* X      = (const float*)d_in[0];
    const float* y_prev = (const float*)d_in[1];
    const float* W1     = (const float*)d_in[2];
    const float* W2     = (const float*)d_in[4];
    const float* W_fc   = (const float*)d_in[6];
    const float* b_fc   = (const float*)d_in[7];
    const float* W_ih   = (const float*)d_in[8];
    const float* W_hh   = (const float*)d_in[9];
    const float* b_ih   = (const float*)d_in[10];
    const float* b_hh   = (const float*)d_in[11];
    const float* W_fin  = (const float*)d_in[12];
    const float* b_fin  = (const float*)d_in[13];
    char* ws = (char*)d_ws;

    hipLaunchKernelGGL(k_prep,  dim3(256), dim3(256), 0, stream, W1, W2, W_hh, ws);
    hipLaunchKernelGGL(k_attn,  dim3(512), dim3(256), 0, stream, X, y_prev, W_fc, b_fc, ws);
    hipLaunchKernelGGL(k_lstm,  dim3(128), dim3(256), 0, stream, W_ih, b_ih, b_hh, ws);
    hipLaunchKernelGGL(k_final, dim3(512), dim3(256), 0, stream, W_fin, b_fin, (float*)d_out, ws);
}

// Round 10
// 550.128 us; speedup vs baseline: 2.1702x; 1.5107x over previous
//
#include <hip/hip_runtime.h>
#include <stdint.h>

typedef __attribute__((ext_vector_type(8))) short short8;
typedef __attribute__((ext_vector_type(8))) unsigned short ushort8_t;
typedef __attribute__((ext_vector_type(4))) float floatx4;

#define T1 127
#define ENC 256
#define HD 256

// workspace offsets (bytes)
#define WHI_OFF   0u            // 1024*256 ushort = 524288
#define WLO_OFF   524288u
#define D0_OFF    1048576u      // 512*128 u64 = 524288  (epoch-tagged d words)
#define D1_OFF    1572864u
#define WEFF_OFF  2097152u      // 256 floats
#define YT_OFF    2099200u      // 512*128 fp32 = 262144
#define CTX_OFF   2361344u      // 512*256 fp32 = 524288
#define DT_OFF    2885632u      // 512*256 fp32 = 524288

__device__ __forceinline__ void split_bf16(float x, unsigned& hi, unsigned& lo) {
    unsigned u = __float_as_uint(x);
    hi = u >> 16;
    float hf = __uint_as_float(hi << 16);
    float r = x - hf;
    unsigned ur = __float_as_uint(r);
    lo = (ur + 0x7fffu + ((ur >> 16) & 1u)) >> 16;
}

__device__ __forceinline__ float sigm_f(float x) { return 1.f / (1.f + __expf(-x)); }
__device__ __forceinline__ float tanh_f(float x) {
    x = fminf(9.f, fmaxf(-9.f, x));
    float e = __expf(2.f * x);
    return (e - 1.f) / (e + 1.f);
}

// One 64-B line sample, agent-coherent (sc0 sc1: bypass L1+L2, served at IC/HBM).
// All 8 u64 words of a thread's poll octet live in this single aligned line and
// are written by one producer wave; per-8B atomicity holds (8-B stores), epoch
// bits are validated per word.
__device__ __forceinline__ void load64_ag(const unsigned long long* p,
                                          uint4& a, uint4& b, uint4& c, uint4& d) {
    asm volatile("global_load_dwordx4 %0, %4, off sc0 sc1\n\t"
                 "global_load_dwordx4 %1, %4, off offset:16 sc0 sc1\n\t"
                 "global_load_dwordx4 %2, %4, off offset:32 sc0 sc1\n\t"
                 "global_load_dwordx4 %3, %4, off offset:48 sc0 sc1\n\t"
                 "s_waitcnt vmcnt(0)"
                 : "=v"(a), "=v"(b), "=v"(c), "=v"(d)
                 : "v"((unsigned long long)p)
                 : "memory");
}

// ---------------- k_prep: weight collapse + W_hh hi/lo split + init ----------------
__global__ __launch_bounds__(256) void k_prep(const float* __restrict__ W1,
                                              const float* __restrict__ W2,
                                              const float* __restrict__ W_hh,
                                              char* __restrict__ ws) {
    const int tid = threadIdx.x, bid = blockIdx.x;
    ushort* Whi = (ushort*)(ws + WHI_OFF);
    ushort* Wlo = (ushort*)(ws + WLO_OFF);
    {
        const int i4 = bid * 256 + tid;   // 0..65535
        float4 v = ((const float4*)W_hh)[i4];
        float vv[4] = {v.x, v.y, v.z, v.w};
        unsigned h[4], l[4];
        #pragma unroll
        for (int j = 0; j < 4; ++j) split_bf16(vv[j], h[j], l[j]);
        *(ushort4*)(Whi + i4 * 4) = make_ushort4((ushort)h[0], (ushort)h[1], (ushort)h[2], (ushort)h[3]);
        *(ushort4*)(Wlo + i4 * 4) = make_ushort4((ushort)l[0], (ushort)l[1], (ushort)l[2], (ushort)l[3]);
    }
    {
        const int idx = bid * 256 + tid;
        if (idx < 32768) ((uint4*)(ws + D0_OFF))[idx] = make_uint4(0, 0, 0, 0);
    }
    if (bid == 0) {
        float acc = 0.f;
        for (int j = 0; j < 128; ++j)
            acc = fmaf(W2[j], W1[j * 768 + 512 + tid], acc);
        ((float*)(ws + WEFF_OFF))[tid] = acc;
    }
}

// ---------------- k_attn: scores -> softmax -> context -> y_tilde ----------------
__global__ __launch_bounds__(256) void k_attn(const float* __restrict__ X,
                                              const float* __restrict__ y_prev,
                                              const float* __restrict__ W_fc,
                                              const float* __restrict__ b_fc,
                                              char* __restrict__ ws) {
    __shared__ float s_lds[128];
    __shared__ float beta[128];
    __shared__ float red[256];
    const int b = blockIdx.x, tid = threadIdx.x;
    const int w = tid >> 6, lane = tid & 63;
    const float* Xb = X + (size_t)b * T1 * ENC;
    const float* weff = (const float*)(ws + WEFF_OFF);
    const float4 w4 = ((const float4*)weff)[lane];
    for (int i = 0; i < 32; ++i) {
        int t = w * 32 + i;
        if (t >= T1) break;
        float4 x4 = ((const float4*)(Xb + t * ENC))[lane];
        float a = x4.x * w4.x + x4.y * w4.y + x4.z * w4.z + x4.w * w4.w;
        for (int m = 32; m >= 1; m >>= 1) a += __shfl_xor(a, m, 64);
        if (lane == 0) s_lds[t] = a;
    }
    __syncthreads();
    if (w == 0) {
        float v0 = s_lds[lane];
        float v1 = (lane + 64 < T1) ? s_lds[lane + 64] : -1e30f;
        float mx = fmaxf(v0, v1);
        for (int m = 32; m >= 1; m >>= 1) mx = fmaxf(mx, __shfl_xor(mx, m, 64));
        float e0 = __expf(v0 - mx);
        float e1 = (lane + 64 < T1) ? __expf(v1 - mx) : 0.f;
        float s = e0 + e1;
        for (int m = 32; m >= 1; m >>= 1) s += __shfl_xor(s, m, 64);
        float inv = 1.f / s;
        beta[lane] = e0 * inv;
        if (lane + 64 < T1) beta[lane + 64] = e1 * inv;
    }
    __syncthreads();
    float acc = 0.f;
    for (int t = 0; t < T1; ++t) acc = fmaf(beta[t], Xb[t * ENC + tid], acc);
    ((float*)(ws + CTX_OFF))[b * ENC + tid] = acc;
    red[tid] = acc * W_fc[tid];
    __syncthreads();
    for (int s = 128; s >= 1; s >>= 1) { if (tid < s) red[tid] += red[tid + s]; __syncthreads(); }
    const float u = red[0] + b_fc[0];
    const float wy = W_fc[256];
    if (tid < T1)
        ((float*)(ws + YT_OFF))[b * 128 + tid] = u + wy * y_prev[b * T1 + tid];
}

// ---------------- k_lstm: persistent sequential LSTM, epoch-in-data exchange ----------------
// R5 topology (proven): 256 blocks, gi = bid>>3 (32 batch groups x 16 batches),
// hj = bid&7 (8 h-tiles x 32 h). W slice resident in VGPRs. d exchanged as u64
// words {hi1, lo1|e1, hi0, lo0|e0} via agent-scope stores. R10 delta: poll is a
// single 64-B line sample per round (one fetch vs 8 scalar loads), no sleep
// until round 16, and the publish store is issued before the own-slice LDS write.
__global__ __launch_bounds__(256, 1) void k_lstm(const float* __restrict__ W_ih,
                                                 const float* __restrict__ b_ih,
                                                 const float* __restrict__ b_hh,
                                                 char* __restrict__ ws) {
    __shared__ __align__(16) ushort ldh[16 * 264];
    __shared__ __align__(16) ushort ldl[16 * 264];
    __shared__ float gbuf[16 * 132];

    const int tid = threadIdx.x, bid = blockIdx.x;
    const int gi = bid >> 3, hj = bid & 7;
    const int w = tid >> 6, lane = tid & 63;
    const int n16 = lane & 15, q = lane >> 4;

    const ushort* Whi = (const ushort*)(ws + WHI_OFF);
    const ushort* Wlo = (const ushort*)(ws + WLO_OFF);
    unsigned long long* Dbuf0 = (unsigned long long*)(ws + D0_OFF);
    unsigned long long* Dbuf1 = (unsigned long long*)(ws + D1_OFF);
    const float* yt = (const float*)(ws + YT_OFF);
    float* dT = (float*)(ws + DT_OFF);

    // resident W fragments: wave w owns N-tiles {2w, 2w+1}; row r = hloc*4 + g
    short8 bfh[2][8], bfl[2][8];
    #pragma unroll
    for (int j = 0; j < 2; ++j) {
        const int r = (2 * w + j) * 16 + n16;          // 0..127
        const int hloc = r >> 2, g = r & 3;
        const int R = g * 256 + hj * 32 + hloc;        // global gate row
        #pragma unroll
        for (int kt = 0; kt < 8; ++kt) {
            bfh[j][kt] = *(const short8*)(Whi + R * 256 + kt * 32 + q * 8);
            bfl[j][kt] = *(const short8*)(Wlo + R * 256 + kt * 32 + q * 8);
        }
    }

    // cell assignment: 16 batches x 32 h = 512 cells, 2 per thread
    const int b_loc = tid & 15, hpair = tid >> 4;      // hpair 0..15
    const int hloc0 = hpair * 2;
    const int bg = gi * 16 + b_loc;
    float wihr[2][4], bihr[2][4];
    #pragma unroll
    for (int jj = 0; jj < 2; ++jj)
        #pragma unroll
        for (int g = 0; g < 4; ++g) {
            const int row = g * HD + hj * 32 + hloc0 + jj;
            wihr[jj][g] = W_ih[row];
            bihr[jj][g] = b_ih[row] + b_hh[row];
        }
    float cc0 = 0.f, cc1 = 0.f;

    // poll/stage assignment: thread covers batch pb = tid>>4, hp8 = tid&15
    // words k = hp8*8 .. hp8*8+7 (cells h = 2k, 2k+1); origin block = hp8>>1
    const int pb = tid >> 4, hp8 = tid & 15;
    const bool own = ((hp8 >> 1) == hj);
    const size_t pbase = (size_t)(gi * 16 + pb) * 128 + hp8 * 8;   // 64B-aligned line

    // pre-zero this thread's full 16-ushort slab segment (d0 = 0) in BOTH planes
    {
        ushort8_t z = {0, 0, 0, 0, 0, 0, 0, 0};
        *(ushort8_t*)(ldh + pb * 264 + hp8 * 16)     = z;
        *(ushort8_t*)(ldh + pb * 264 + hp8 * 16 + 8) = z;
        *(ushort8_t*)(ldl + pb * 264 + hp8 * 16)     = z;
        *(ushort8_t*)(ldl + pb * 264 + hp8 * 16 + 8) = z;
    }

    for (int t = 1; t <= T1; ++t) {
        const float ytv = yt[bg * 128 + (t - 1)];   // prefetch, independent of d
        // ---- poll d_{t-1}: one 64-B line sample per round ----
        if (!own) {
            unsigned long long* Dsrc = ((t - 1) & 1) ? Dbuf1 : Dbuf0;
            const unsigned e = (unsigned)(t - 1) & 3u;
            unsigned lo[8], hi[8];
            for (int round = 0; ; ++round) {
                uint4 A, B, C, D;
                load64_ag(&Dsrc[pbase], A, B, C, D);
                lo[0] = A.x; hi[0] = A.y; lo[1] = A.z; hi[1] = A.w;
                lo[2] = B.x; hi[2] = B.y; lo[3] = B.z; hi[3] = B.w;
                lo[4] = C.x; hi[4] = C.y; lo[5] = C.z; hi[5] = C.w;
                lo[6] = D.x; hi[6] = D.y; lo[7] = D.z; hi[7] = D.w;
                bool ok = true;
                #pragma unroll
                for (int i = 0; i < 8; ++i) {
                    unsigned ep = (lo[i] & 1u) | ((hi[i] & 1u) << 1);
                    ok &= (ep == e);
                }
                if (ok) break;
                if (round >= 16) __builtin_amdgcn_s_sleep(1);
            }
            // decode: 16 hi + 16 lo ushorts -> two b128 stores per plane
            ushort hv[16], lv[16];
            #pragma unroll
            for (int i = 0; i < 8; ++i) {
                hv[2 * i]     = (ushort)(lo[i] >> 16);
                hv[2 * i + 1] = (ushort)(hi[i] >> 16);
                lv[2 * i]     = (ushort)(lo[i] & 0xFFFEu);
                lv[2 * i + 1] = (ushort)(hi[i] & 0xFFFEu);
            }
            ushort8_t H0, L0, H1, L1;
            #pragma unroll
            for (int i = 0; i < 8; ++i) { H0[i] = hv[i]; L0[i] = lv[i]; H1[i] = hv[8 + i]; L1[i] = lv[8 + i]; }
            *(ushort8_t*)(ldh + pb * 264 + hp8 * 16)     = H0;
            *(ushort8_t*)(ldh + pb * 264 + hp8 * 16 + 8) = H1;
            *(ushort8_t*)(ldl + pb * 264 + hp8 * 16)     = L0;
            *(ushort8_t*)(ldl + pb * 264 + hp8 * 16 + 8) = L1;
        }
        __syncthreads();
        // MFMA: gates[16b x 128r] = d[16x256] @ Wslice^T  (hi*hi + lo*hi + hi*lo)
        floatx4 acc0 = {0.f, 0.f, 0.f, 0.f}, acc1 = {0.f, 0.f, 0.f, 0.f};
        #pragma unroll
        for (int kt = 0; kt < 8; ++kt) {
            short8 ah = *(const short8*)(ldh + n16 * 264 + kt * 32 + q * 8);
            short8 al = *(const short8*)(ldl + n16 * 264 + kt * 32 + q * 8);
            acc0 = __builtin_amdgcn_mfma_f32_16x16x32_bf16(ah, bfh[0][kt], acc0, 0, 0, 0);
            acc0 = __builtin_amdgcn_mfma_f32_16x16x32_bf16(al, bfh[0][kt], acc0, 0, 0, 0);
            acc0 = __builtin_amdgcn_mfma_f32_16x16x32_bf16(ah, bfl[0][kt], acc0, 0, 0, 0);
            acc1 = __builtin_amdgcn_mfma_f32_16x16x32_bf16(ah, bfh[1][kt], acc1, 0, 0, 0);
            acc1 = __builtin_amdgcn_mfma_f32_16x16x32_bf16(al, bfh[1][kt], acc1, 0, 0, 0);
            acc1 = __builtin_amdgcn_mfma_f32_16x16x32_bf16(ah, bfl[1][kt], acc1, 0, 0, 0);
        }
        // scatter C-frags: row m = q*4+reg (batch), col = tile*16+n16 (gate row)
        #pragma unroll
        for (int reg = 0; reg < 4; ++reg) {
            gbuf[(q * 4 + reg) * 132 + (2 * w) * 16 + n16]     = acc0[reg];
            gbuf[(q * 4 + reg) * 132 + (2 * w + 1) * 16 + n16] = acc1[reg];
        }
        __syncthreads();
        // LSTM cell: 2 cells per thread
        float dnew[2];
        #pragma unroll
        for (int jj = 0; jj < 2; ++jj) {
            const int base = b_loc * 132 + (hloc0 + jj) * 4;
            float pi = gbuf[base + 0] + ytv * wihr[jj][0] + bihr[jj][0];
            float pf = gbuf[base + 1] + ytv * wihr[jj][1] + bihr[jj][1];
            float pg = gbuf[base + 2] + ytv * wihr[jj][2] + bihr[jj][2];
            float po = gbuf[base + 3] + ytv * wihr[jj][3] + bihr[jj][3];
            float ig = sigm_f(pi), fg = sigm_f(pf), og = sigm_f(po);
            float gg = tanh_f(pg);
            float& c = jj ? cc1 : cc0;
            c = fg * c + ig * gg;
            dnew[jj] = og * tanh_f(c);
        }
        if (t < T1) {
            const unsigned e = (unsigned)t & 3u;
            unsigned h0, l0, h1, l1;
            split_bf16(dnew[0], h0, l0);
            split_bf16(dnew[1], h1, l1);
            l0 = (l0 & 0xFFFEu) | (e & 1u);
            l1 = (l1 & 0xFFFEu) | ((e >> 1) & 1u);
            // publish FIRST (earliest visibility for the 7 consumer blocks)
            unsigned long long wv = ((unsigned long long)h1 << 48) |
                                    ((unsigned long long)l1 << 32) |
                                    ((unsigned long long)h0 << 16) |
                                    (unsigned long long)l0;
            unsigned long long* Ddst = (t & 1) ? Dbuf1 : Dbuf0;
            __hip_atomic_store(&Ddst[(size_t)bg * 128 + hj * 16 + hpair], wv,
                               __ATOMIC_RELAXED, __HIP_MEMORY_SCOPE_AGENT);
            // own slice -> directly into next step's LDS slab (barrier-ordered)
            *(ushort2*)(ldh + b_loc * 264 + hj * 32 + hloc0) =
                make_ushort2((ushort)h0, (ushort)h1);
            *(ushort2*)(ldl + b_loc * 264 + hj * 32 + hloc0) =
                make_ushort2((ushort)(l0 & 0xFFFEu), (ushort)(l1 & 0xFFFEu));
        } else {
            *(float2*)(dT + bg * 256 + hj * 32 + hloc0) = make_float2(dnew[0], dnew[1]);
        }
    }
}

// ---------------- k_final: y_pred = W_final . [dT, context] + b ----------------
__global__ __launch_bounds__(256) void k_final(const float* __restrict__ W_final,
                                               const float* __restrict__ b_final,
                                               float* __restrict__ out,
                                               char* __restrict__ ws) {
    __shared__ float red[256];
    const int b = blockIdx.x, tid = threadIdx.x;
    const float* dT = (const float*)(ws + DT_OFF);
    const float* ctx = (const float*)(ws + CTX_OFF);
    float v = W_final[tid] * dT[b * 256 + tid] + W_final[256 + tid] * ctx[b * 256 + tid];
    red[tid] = v;
    __syncthreads();
    for (int s = 128; s >= 1; s >>= 1) { if (tid < s) red[tid] += red[tid + s]; __syncthreads(); }
    if (tid == 0) out[b] = red[0] + b_final[0];
}

extern "C" void kernel_launch(void* const* d_in, const int* in_sizes, int n_in,
                              void* d_out, int out_size, void* d_ws, size_t ws_size,
                              hipStream_t stream) {
    const float* X      = (const float*)d_in[0];
    const float* y_prev = (const float*)d_in[1];
    const float* W1     = (const float*)d_in[2];
    const float* W2     = (const float*)d_in[4];
    const float* W_fc   = (const float*)d_in[6];
    const float* b_fc   = (const float*)d_in[7];
    const float* W_ih   = (const float*)d_in[8];
    const float* W_hh   = (const float*)d_in[9];
    const float* b_ih   = (const float*)d_in[10];
    const float* b_hh   = (const float*)d_in[11];
    const float* W_fin  = (const float*)d_in[12];
    const float* b_fin  = (const float*)d_in[13];
    char* ws = (char*)d_ws;

    hipLaunchKernelGGL(k_prep,  dim3(256), dim3(256), 0, stream, W1, W2, W_hh, ws);
    hipLaunchKernelGGL(k_attn,  dim3(512), dim3(256), 0, stream, X, y_prev, W_fc, b_fc, ws);
    hipLaunchKernelGGL(k_lstm,  dim3(256), dim3(256), 0, stream, W_ih, b_ih, b_hh, ws);
    hipLaunchKernelGGL(k_final, dim3(512), dim3(256), 0, stream, W_fin, b_fin, (float*)d_out, ws);
}